// Round 3
// 107.606 us; speedup vs baseline: 1.0693x; 1.0693x over previous
//
#include <hip/hip_runtime.h>

// Quantum conv circuit, 16 qubits, batch 16.
// Round 11c (semantics fix of r11b): v_permlane32_swap_b32 returns
//   r[0] = (lane<32)? self : partner   == x0 (amplitude with bit5=0)
//   r[1] = (lane<32)? partner : self   == x1 (amplitude with bit5=1)
// r11b had x0/x1 bound inverted in lgate32 (gate columns swapped -> stray X gates)
// and the sigma1a partner-select inverted (swap became a no-op). Both fixed.
//  - k_setup folded away: every block builds the 60-gate table in LDS (f32 sincosf);
//    p1 block 0 exports table to global for p2/p4, zeroes out[].
//  - diag4 = signed half-angle SUM + one __sincosf per slot (tbl[480+g] = theta3/2).
//  - mask-32 lane gates + sigma1a via permlane32_swap (VALU, no DS/lgkmcnt).
//  - lgate slimmed: coefficient-only select, new = A*self + B*partner.
// 512 blocks x 512 threads, 4 amps/thread, 11-bit tiles. st = float2[16][65536] at d_ws;
// tbl (540 floats) at d_ws + 8MB. Bit convention: wire w <-> flat bit p = 15-w.
// Gate index: L1d0(p)=15-p, L1d1(p)=16+(15-p), L2d0(p)=32+(15-p)/2, L2d1(p)=40+(15-p)/2,
//             L3d0(p)=48+(15-p)/4, L3d1(p)=52+(15-p)/4, L4d0(p)=56+(15-p)/8, L4d1(p)=58+(15-p)/8.

#define DEV __device__ __forceinline__

__device__ static const unsigned char G_CP[60] = {
  15,14,13,12,11,10,9,8,7,6,5,4,3,2,1,0,
  15,14,13,12,11,10,9,8,7,6,5,4,3,2,1,0,
  15,13,11,9,7,5,3,1,
  15,13,11,9,7,5,3,1,
  15,11,7,3,
  15,11,7,3,
  15,7,
  15,7
};
__device__ static const unsigned char G_CQ[60] = {
  14,13,12,11,10,9,8,7,6,5,4,3,2,1,0,15,
  14,13,12,11,10,9,8,7,6,5,4,3,2,1,0,15,
  13,11,9,7,5,3,1,15,
  13,11,9,7,5,3,1,15,
  11,7,3,15,
  11,7,3,15,
  7,15,
  7,15
};

DEV float2 F2(float x, float y){ float2 r; r.x = x; r.y = y; return r; }
DEV float2 cmulf(float2 a, float2 b){ return F2(a.x*b.x - a.y*b.y, a.x*b.y + a.y*b.x); }
DEV int swz(int j){ return j ^ ((j>>4)&15) ^ ((j>>8)&15); }

// ---- permlane32_swap(a,b): r[0] = a.lo | b.lo->hi ; r[1] = a.hi->lo | b.hi.
// Seeding both with the same value v gives r[0]=x0, r[1]=x1 (see header). ----
#if __has_builtin(__builtin_amdgcn_permlane32_swap)
#define HAVE_PLS 1
// in/out: x0 and x1 both hold v on entry; on exit x0 = (lane<32)? self:partner,
// x1 = (lane<32)? partner:self.
DEV void plswap01(float &x0, float &x1){
  auto r = __builtin_amdgcn_permlane32_swap(__float_as_uint(x0), __float_as_uint(x1), false, false);
  x0 = __uint_as_float((unsigned)r[0]);
  x1 = __uint_as_float((unsigned)r[1]);
}
#else
#define HAVE_PLS 0
#endif

// gate on register slot bit SB (free)
template<int SB>
DEV void gate4(float2* a, const float* __restrict__ g){
  float u00r=g[0],u00i=g[1],u01r=g[2],u01i=g[3],u10r=g[4],u10i=g[5],u11r=g[6],u11i=g[7];
  #pragma unroll
  for (int m=0;m<2;m++){
    int i0 = (SB==0) ? (m<<1) : m;
    int i1 = i0 | (1<<SB);
    float2 x0=a[i0], x1=a[i1];
    a[i0] = F2(u00r*x0.x - u00i*x0.y + u01r*x1.x - u01i*x1.y,
               u00r*x0.y + u00i*x0.x + u01r*x1.y + u01i*x1.x);
    a[i1] = F2(u10r*x0.x - u10i*x0.y + u11r*x1.x - u11i*x1.y,
               u10r*x0.y + u10i*x0.x + u11r*x1.y + u11i*x1.x);
  }
}

// gate on LANE bit (partner via shfl_xor; no barrier).
// new = A*self + B*partner with A = h? u11:u00, B = h? u10:u01  (coef-select only).
DEV void lgate(float2* a, const float* __restrict__ g, int mask, int lane){
  bool h = (lane & mask) != 0;
  float Ar = h ? g[6] : g[0], Ai = h ? g[7] : g[1];
  float Br = h ? g[4] : g[2], Bi = h ? g[5] : g[3];
  #pragma unroll
  for (int s=0;s<4;s++){
    float px = __shfl_xor(a[s].x, mask);
    float py = __shfl_xor(a[s].y, mask);
    a[s] = F2(Ar*a[s].x - Ai*a[s].y + Br*px - Bi*py,
              Ar*a[s].y + Ai*a[s].x + Br*py + Bi*px);
  }
}

// mask-32 lane gate via permlane32_swap (no DS pipe, no lgkmcnt stall).
// c0 multiplies x0, c1 multiplies x1:  h=0 -> new = u00*x0 + u01*x1 (row 0);
//                                      h=1 -> new = u10*x0 + u11*x1 (row 1).
DEV void lgate32(float2* a, const float* __restrict__ g, int lane){
#if HAVE_PLS
  bool h = (lane & 32) != 0;
  float c0r = h ? g[4] : g[0], c0i = h ? g[5] : g[1];
  float c1r = h ? g[6] : g[2], c1i = h ? g[7] : g[3];
  #pragma unroll
  for (int s=0;s<4;s++){
    float x0x = a[s].x, x1x = a[s].x, x0y = a[s].y, x1y = a[s].y;
    plswap01(x0x, x1x); plswap01(x0y, x1y);
    a[s] = F2(c0r*x0x - c0i*x0y + c1r*x1x - c1i*x1y,
              c0r*x0y + c0i*x0x + c1r*x1y + c1i*x1x);
  }
#else
  lgate(a, g, 32, lane);
#endif
}

// CNOT with control lane-bit cmask, target lane-bit tmask (in-wave cond pair-swap)
DEV void cswap(float2* a, int cmask, int tmask, int lane){
  bool c = (lane & cmask) != 0;
  #pragma unroll
  for (int s=0;s<4;s++){
    float px = __shfl_xor(a[s].x, tmask);
    float py = __shfl_xor(a[s].y, tmask);
    if (c){ a[s].x = px; a[s].y = py; }
  }
}

// RZZ round, couplings [C0,C0+N). hh[g] = theta3(g)/2. Ib = true index with the two
// reg bits zeroed. Phase angle = sum of +-hh (sign + if bits differ), one sincos/slot.
template<int C0,int N,unsigned M0,unsigned M1>
DEV void diag4(float2* a, const float* __restrict__ hh, unsigned Ib){
  const unsigned regmask = M0|M1;
  float base = 0.f;
  #pragma unroll
  for (int k=0;k<N;k++){
    const int p = G_CP[C0+k], q = G_CQ[C0+k];
    if ( !(((1u<<p)|(1u<<q)) & regmask) ){
      float h = hh[C0+k];
      unsigned x = ((Ib>>p) ^ (Ib>>q)) & 1u;
      base += x ? h : -h;
    }
  }
  #pragma unroll
  for (int r=0;r<4;r++){
    unsigned Ir = Ib ^ ((r&1)?M0:0u) ^ ((r&2)?M1:0u);
    float ph = base;
    #pragma unroll
    for (int k=0;k<N;k++){
      const int p = G_CP[C0+k], q = G_CQ[C0+k];
      if ( ((1u<<p)|(1u<<q)) & regmask ){
        float h = hh[C0+k];
        unsigned x = ((Ir>>p) ^ (Ir>>q)) & 1u;
        ph += x ? h : -h;
      }
    }
    float c, s;
    __sincosf(ph, &s, &c);
    a[r] = cmulf(a[r], F2(c, s));
  }
}

// ---- per-block gate-table build (f32; entry g in [0,60)) ----
DEV void build_entry(float* sh, const float* __restrict__ p0, const float* __restrict__ p1,
                     const float* __restrict__ p2, const float* __restrict__ p3, int g){
  int d, j, n; const float* P;
  if (g < 32)      { n=16; d=(g>>4)&1; j=g&15; P=p0; }
  else if (g < 48) { n=8;  d=(g>>3)&1; j=g&7;  P=p1; }
  else if (g < 56) { n=4;  d=(g>>2)&1; j=g&3;  P=p2; }
  else             { n=2;  d=(g>>1)&1; j=g&1;  P=p3; }
  int base = 4*j + 4*n*d;
  float th0 = P[base+0], th1 = P[base+1], th2 = P[base+2], th3 = P[base+3];
  float c0,s0,ca,sa,c2,s2;
  sincosf(0.5f*th0, &s0, &c0);
  sincosf(0.5f*th1, &sa, &ca);
  sincosf(0.5f*th2, &s2, &c2);
  float B00r =  ca*c0, B00i = -sa*c0;
  float B01r = -sa*s0, B01i = -ca*s0;
  float B10r =  sa*s0, B10i = -ca*s0;
  float B11r =  ca*c0, B11i =  sa*c0;
  float* o8 = sh + g*8;
  o8[0]=c2*B00r + s2*B10i; o8[1]=c2*B00i - s2*B10r;
  o8[2]=c2*B01r + s2*B11i; o8[3]=c2*B01i - s2*B11r;
  o8[4]=s2*B00i + c2*B10r; o8[5]=-s2*B00r + c2*B10i;
  o8[6]=s2*B01i + c2*B11r; o8[7]=-s2*B01r + c2*B11i;
  sh[480 + g] = 0.5f*th3;
}

// ---- global index maps (verbatim r9, verified) ----
DEV unsigned Ib2(int j, int o){ return (unsigned)((j&63) | (o<<6) | ((j>>6)<<11)); }
DEV unsigned Ic(int j, int o){
  return (unsigned)( ((j&1)<<1) | (((j>>1)&1)<<3) | (((j>>2)&1)<<5)
       | (((j>>3)&63)<<6) | (((j>>9)&1)<<13) | (((j>>10)&1)<<15)
       | (o&1) | (((o>>1)&1)<<2) | (((o>>2)&1)<<4) | (((o>>3)&1)<<12) | (((o>>4)&1)<<14) );
}
DEV unsigned s1b(unsigned I){ return I ^ ((I & 0xA02Au) >> 1); }

// ======== pass 1: L1d0 g0..g10. inner j = g0..10, outer o = g11..15 ========
// Layout A: reg=(j0,j1), lane=(j2..j7), wave=(j8,j9,j10). One LDS exchange ->
// Layout B: reg=(j8,j9), lane=(j0..j4,j10), wave=(j5,j6,j7).
// Also: builds gate table in LDS (all blocks); block 0 exports to global + zeroes out.
__global__ __launch_bounds__(512, 4)
void k_p1(const float* __restrict__ xre, const float* __restrict__ xim,
          const float* __restrict__ pp0, const float* __restrict__ pp1,
          const float* __restrict__ pp2, const float* __restrict__ pp3,
          float* __restrict__ tbl, float2* __restrict__ st, float* __restrict__ out){
  const int t = threadIdx.x, lane = t & 63, wv = t >> 6;
  const int batch = blockIdx.x >> 5, o = blockIdx.x & 31;
  const unsigned hi = ((unsigned)batch<<16) | ((unsigned)o<<11);
  __shared__ float2 lds[2048];
  __shared__ float sh[544];
  float2 a[4];
  { // load layout A: jA = s | (t<<2)   (loads issue before table build -> overlap)
    unsigned base = hi | ((unsigned)t<<2);
    float4 re = *(const float4*)(xre + base);
    float4 im = *(const float4*)(xim + base);
    a[0]=F2(re.x,im.x); a[1]=F2(re.y,im.y); a[2]=F2(re.z,im.z); a[3]=F2(re.w,im.w);
  }
  if (t < 60) build_entry(sh, pp0, pp1, pp2, pp3, t);
  if (blockIdx.x == 0 && t >= 64 && t < 80) out[t - 64] = 0.f;
  __syncthreads();
  if (blockIdx.x == 0){
    for (int i = t; i < 540; i += 512) tbl[i] = sh[i];
  }
  #define LTB(i) (sh + (i)*8)
  gate4<0>(a, LTB(15)); gate4<1>(a, LTB(14));            // g0,g1 (reg)
  lgate(a, LTB(13), 1, lane);  lgate(a, LTB(12), 2, lane);   // g2,g3
  lgate(a, LTB(11), 4, lane);  lgate(a, LTB(10), 8, lane);   // g4,g5
  lgate(a, LTB(9), 16, lane);  lgate32(a, LTB(8), lane);     // g6,g7
  #pragma unroll
  for (int s=0;s<4;s++) lds[swz((t<<2)|s)] = a[s];
  __syncthreads();
  #pragma unroll
  for (int s=0;s<4;s++){
    int jB = (lane&31) | (wv<<5) | (s<<8) | ((lane>>5)<<10);
    a[s] = lds[swz(jB)];
  }
  gate4<0>(a, LTB(7)); gate4<1>(a, LTB(6));              // g8,g9 (reg)
  lgate32(a, LTB(5), lane);                              // g10 (lane bit5)
  #pragma unroll
  for (int s=0;s<4;s++){
    int jB = (lane&31) | (wv<<5) | (s<<8) | ((lane>>5)<<10);
    st[hi | (unsigned)jB] = a[s];
  }
  #undef LTB
}

#define TBL(i) (tbl + (i)*8)

// ======== pass 2: L1d0 g11..15, D0, L1d1 {g0..5, g11..15}. outer o = g6..g10 ========
// j0..j5 = g0..g5, j6..j10 = g11..g15.
// Layout A: reg=(j10,j9)=(g15,g14); lane bits0-2=(j8,j7,j6)=(g13,g12,g11),
//           bits3-5=(j0,j1,j2)=(g0,g1,g2); wave=(j3,j4,j5)=(g3,g4,g5).
// Layout B: reg=(j3,j4)=(g3,g4); lane=(j0,j1,j2,j5,j9,j10); wave=(j6,j7,j8).
__global__ __launch_bounds__(512, 4)
void k_p2(const float* __restrict__ tbl, float2* __restrict__ st){
  const int t = threadIdx.x, lane = t & 63, wv = t >> 6;
  const int batch = blockIdx.x >> 5, o = blockIdx.x & 31;
  const unsigned bb = (unsigned)batch<<16;
  __shared__ float2 lds[2048];
  float2 a[4];
  int jA0 = ((lane&1)<<8) | (((lane>>1)&1)<<7) | (((lane>>2)&1)<<6)
          | (((lane>>3)&1)<<0) | (((lane>>4)&1)<<1) | (((lane>>5)&1)<<2) | (wv<<3);
  #pragma unroll
  for (int s=0;s<4;s++){
    int jA = jA0 | ((s&1)<<10) | (((s>>1)&1)<<9);
    a[s] = st[bb | Ib2(jA, o)];
  }
  gate4<0>(a, TBL(0)); gate4<1>(a, TBL(1));              // L1d0 g15,g14 (reg)
  lgate(a, TBL(2), 1, lane); lgate(a, TBL(3), 2, lane); lgate(a, TBL(4), 4, lane); // g13,g12,g11
  diag4<0,16, (1u<<15),(1u<<14)>(a, tbl+480, Ib2(jA0, o));   // D0
  lgate(a, TBL(20), 4, lane); lgate(a, TBL(19), 2, lane); lgate(a, TBL(18), 1, lane); // L1d1 g11,g12,g13
  gate4<1>(a, TBL(17)); gate4<0>(a, TBL(16));            // L1d1 g14,g15
  lgate(a, TBL(31), 8, lane); lgate(a, TBL(30), 16, lane); lgate32(a, TBL(29), lane); // g0,g1,g2
  #pragma unroll
  for (int s=0;s<4;s++){
    int jA = jA0 | ((s&1)<<10) | (((s>>1)&1)<<9);
    lds[swz(jA)] = a[s];
  }
  __syncthreads();
  int jB0 = (lane&7) | (((lane>>3)&1)<<5) | (wv<<6)
          | (((lane>>4)&1)<<9) | (((lane>>5)&1)<<10);
  #pragma unroll
  for (int s=0;s<4;s++){
    int jB = jB0 | ((s&1)<<3) | (((s>>1)&1)<<4);
    a[s] = lds[swz(jB)];
  }
  gate4<0>(a, TBL(28)); gate4<1>(a, TBL(27));            // L1d1 g3,g4 (reg)
  lgate(a, TBL(26), 8, lane);                            // L1d1 g5 (lane bit3)
  #pragma unroll
  for (int s=0;s<4;s++){
    int jB = jB0 | ((s&1)<<3) | (((s>>1)&1)<<4);
    st[bb | Ib2(jB, o)] = a[s];
  }
}

// ======== pass 4: s1b-gather, L1d1 g6..10, D1, s1a, L2..L4, measure ========
// j-map (Ic): j0..j10 -> g{1,3,5,6,7,8,9,10,11,13,15}; outer o -> g{0,2,4,12,14}.
// Layout A: reg=(j3,j4)=(g6,g7); lane bits0-2=(j0,j1,j2)=(g1,g3,g5),
//           bits3-5=(j5,j6,j7)=(g8,g9,g10); wave=(j8,j9,j10)=(g11,g13,g15).
// Layout B: reg=(j0,j1)=(g1,g3); lane=(j2,j4,j6,j8,j9,j10)=(g5,g7,g9,g11,g13,g15);
//           wave=(j3,j5,j7)=(g6,g8,g10).
__global__ __launch_bounds__(512, 4)
void k_p4(const float* __restrict__ tbl, float2* __restrict__ st, float* __restrict__ out){
  const int t = threadIdx.x, lane = t & 63, wv = t >> 6;
  const int batch = blockIdx.x >> 5, o = blockIdx.x & 31;
  const unsigned bb = (unsigned)batch<<16;
  __shared__ float2 lds[2048];
  __shared__ float red[8];
  float2 a[4];
  int jA0 = (lane&7) | (((lane>>3)&7)<<5) | (wv<<8);
  #pragma unroll
  for (int s=0;s<4;s++){
    int jA = jA0 | ((s&1)<<3) | (((s>>1)&1)<<4);
    a[s] = st[bb | s1b(Ic(jA, o))];
  }
  gate4<0>(a, TBL(25)); gate4<1>(a, TBL(24));            // L1d1 g6,g7 (reg)
  lgate(a, TBL(23), 8, lane); lgate(a, TBL(22), 16, lane); lgate32(a, TBL(21), lane); // g8,g9,g10
  diag4<16,16, (1u<<6),(1u<<7)>(a, tbl+480, s1b(Ic(jA0, o))); // D1 (index = amplitude's own)
  // sigma1a: (g11->g10): ctrl = wave bit0, tgt = lane bit5 (wave-uniform swap).
  // partner = (lane&32)? x0 : x1  (x0/x1 from plswap01).
  if (wv & 1){
#if HAVE_PLS
    #pragma unroll
    for (int s=0;s<4;s++){
      float x0x=a[s].x, x1x=a[s].x, x0y=a[s].y, x1y=a[s].y;
      plswap01(x0x, x1x); plswap01(x0y, x1y);
      a[s].x = (lane & 32) ? x0x : x1x;
      a[s].y = (lane & 32) ? x0y : x1y;
    }
#else
    #pragma unroll
    for (int s=0;s<4;s++){ a[s].x = __shfl_xor(a[s].x, 32); a[s].y = __shfl_xor(a[s].y, 32); }
#endif
  }
  cswap(a, 16, 8, lane);                                 // (g9->g8)
  { float2 tmp=a[2]; a[2]=a[3]; a[3]=tmp; }              // (g7->g6): reg ctrl s1, tgt s0
  #pragma unroll
  for (int s=0;s<4;s++){
    int jA = jA0 | ((s&1)<<3) | (((s>>1)&1)<<4);
    lds[swz(jA)] = a[s];
  }
  __syncthreads();
  int jB0 = ((lane&1)<<2) | (((lane>>1)&1)<<4) | (((lane>>2)&1)<<6)
          | (((lane>>3)&1)<<8) | (((lane>>4)&1)<<9) | (((lane>>5)&1)<<10)
          | ((wv&1)<<3) | (((wv>>1)&1)<<5) | (((wv>>2)&1)<<7);
  #pragma unroll
  for (int s=0;s<4;s++) a[s] = lds[swz(jB0 | (s&1) | (((s>>1)&1)<<1))];
  const unsigned IbB = Ic(jB0, o);
  // L2d0: g1,g3 (reg); g5,g7,g9,g11,g13,g15 (lane bits 0..5)
  gate4<0>(a, TBL(39)); gate4<1>(a, TBL(38));
  lgate(a, TBL(37), 1, lane); lgate(a, TBL(36), 2, lane); lgate(a, TBL(35), 4, lane);
  lgate(a, TBL(34), 8, lane); lgate(a, TBL(33), 16, lane); lgate32(a, TBL(32), lane);
  diag4<32,8, 2u,8u>(a, tbl+480, IbB);                   // D2_0
  // L2d1
  gate4<0>(a, TBL(47)); gate4<1>(a, TBL(46));
  lgate(a, TBL(45), 1, lane); lgate(a, TBL(44), 2, lane); lgate(a, TBL(43), 4, lane);
  lgate(a, TBL(42), 8, lane); lgate(a, TBL(41), 16, lane); lgate32(a, TBL(40), lane);
  diag4<40,8, 2u,8u>(a, tbl+480, IbB);                   // D2_1
  // sigma2: (g15->g13),(g11->g9),(g7->g5) in-wave; (g3->g1) reg
  cswap(a, 32, 16, lane); cswap(a, 8, 4, lane); cswap(a, 2, 1, lane);
  { float2 tmp=a[2]; a[2]=a[3]; a[3]=tmp; }
  // L3d0 {g15,g11,g7,g3}
  lgate32(a, TBL(48), lane); lgate(a, TBL(49), 8, lane); lgate(a, TBL(50), 2, lane);
  gate4<1>(a, TBL(51));
  diag4<48,4, 2u,8u>(a, tbl+480, IbB);                   // D3_0
  // L3d1
  lgate32(a, TBL(52), lane); lgate(a, TBL(53), 8, lane); lgate(a, TBL(54), 2, lane);
  gate4<1>(a, TBL(55));
  diag4<52,4, 2u,8u>(a, tbl+480, IbB);                   // D3_1
  // sigma3: (g15->g11) in-wave; (g7->g3): ctrl lane bit1, tgt reg s1
  cswap(a, 32, 8, lane);
  if (lane & 2){
    float2 t0=a[0]; a[0]=a[2]; a[2]=t0;
    float2 t1=a[1]; a[1]=a[3]; a[3]=t1;
  }
  // L4d0 {g15,g7}, D4_0, L4d1 g15
  lgate32(a, TBL(56), lane); lgate(a, TBL(57), 2, lane);
  diag4<56,2, 2u,8u>(a, tbl+480, IbB);
  lgate32(a, TBL(58), lane);
  // sigma4, D4_1, L4d1(g7) dropped: invariant for the g15 marginal.
  // measure Z on g15 = lane bit5
  float sl = 0.f;
  #pragma unroll
  for (int s=0;s<4;s++) sl += a[s].x*a[s].x + a[s].y*a[s].y;
  float sg = (lane & 32) ? -sl : sl;
  #pragma unroll
  for (int off=32; off>0; off>>=1) sg += __shfl_down(sg, off);
  __syncthreads();
  if ((t & 63) == 0) red[wv] = sg;
  __syncthreads();
  if (t == 0){
    float tot = 0.f;
    #pragma unroll
    for (int w=0; w<8; w++) tot += red[w];
    atomicAdd(out + batch, tot);
  }
}

extern "C" void kernel_launch(void* const* d_in, const int* in_sizes, int n_in,
                              void* d_out, int out_size, void* d_ws, size_t ws_size,
                              hipStream_t stream) {
  const float* xre = (const float*)d_in[0];
  const float* xim = (const float*)d_in[1];
  const float* p0  = (const float*)d_in[2];
  const float* p1  = (const float*)d_in[3];
  const float* p2  = (const float*)d_in[4];
  const float* p3  = (const float*)d_in[5];
  float* out = (float*)d_out;
  float2* st = (float2*)d_ws;                           // 8 MB state
  float* tbl = (float*)((char*)d_ws + (8u<<20));        // 540-float gate table

  k_p1<<<512, 512, 0, stream>>>(xre, xim, p0, p1, p2, p3, tbl, st, out);
  k_p2<<<512, 512, 0, stream>>>(tbl, st);
  k_p4<<<512, 512, 0, stream>>>(tbl, st, out);
}

// Round 4
// 105.001 us; speedup vs baseline: 1.0958x; 1.0248x over previous
//
#include <hip/hip_runtime.h>

// Quantum conv circuit, 16 qubits, batch 16.
// Round 12: TWO-pass restructure (from r11c's 3-pass, 107.6us).
// Diagonals (RZZ) depend only on an amplitude's own bits -> applicable in any pass.
// Pass A: tile b0..b11 (outer b12..15): L1d0 b0..b11, D0 (0,1)..(10,11),
//         L1d1 b1..b10, D1 (1,2)..(9,10), sigma1 CNOTs (3->2),(5->4),(7->6),(9->8).
// Pass B: tile {b0,b1,b3,b5,b7,b9,b10,b11,b12..b15} (outer b2,b4,b6,b8 - retired):
//         L1d0 b12..15, D0 rest, L1d1 {b0,b11..b15}, D1 rest, sigma1 rest,
//         L2..L4 + measure (verbatim r11c p4 tail: reg=(b1,b3), lane=(b5..b15)).
// 256 blocks x 1024 threads, 4 amps/thread, 12-bit tiles. reg=(b10,b11) at the A/B
// boundary in BOTH passes -> pass-A store linear+contiguous, pass-B gather 32B/thread.
// st = float2[16][65536] at d_ws; tbl (540 floats) at d_ws + 8MB. bit p = 15-wire.
// Gate idx: L1d0(p)=15-p, L1d1(p)=16+(15-p), L2d0(p)=32+(15-p)/2, L2d1(p)=40+(15-p)/2,
//           L3d0(p)=48+(15-p)/4, L3d1(p)=52+(15-p)/4, L4d0(p)=56+(15-p)/8, L4d1=58,59.

#define DEV __device__ __forceinline__

__device__ static const unsigned char G_CP[60] = {
  15,14,13,12,11,10,9,8,7,6,5,4,3,2,1,0,
  15,14,13,12,11,10,9,8,7,6,5,4,3,2,1,0,
  15,13,11,9,7,5,3,1,
  15,13,11,9,7,5,3,1,
  15,11,7,3,
  15,11,7,3,
  15,7,
  15,7
};
__device__ static const unsigned char G_CQ[60] = {
  14,13,12,11,10,9,8,7,6,5,4,3,2,1,0,15,
  14,13,12,11,10,9,8,7,6,5,4,3,2,1,0,15,
  13,11,9,7,5,3,1,15,
  13,11,9,7,5,3,1,15,
  11,7,3,15,
  11,7,3,15,
  7,15,
  7,15
};

DEV float2 F2(float x, float y){ float2 r; r.x = x; r.y = y; return r; }
DEV float2 cmulf(float2 a, float2 b){ return F2(a.x*b.x - a.y*b.y, a.x*b.y + a.y*b.x); }
// pass-A exchange swizzle (A-write lanes j2..j7 / B-read lanes j8,j9,j6,j7,j4,j5:
// bank-pair bits get 4 indep lane combos both ways)
DEV int swz(int j){ return j ^ ((j>>4)&15) ^ ((j>>8)&15); }
// pass-B exchange swizzle (A lanes m8..m11,m0,m1 / B lanes m3,m4,m5,m7,m9,m11)
DEV int sw2(int m){
  return m ^ ((m>>9)&1) ^ (((m>>11)&1)<<1)
           ^ ((((m>>3)&1)^((m>>8)&1))<<2)
           ^ ((((m>>4)&1)^((m>>5)&1)^((m>>10)&1))<<3);
}

// ---- permlane32_swap(a,b): r[0] = (lane<32)? self:partner = x0;
//      r[1] = (lane<32)? partner:self = x1.  (HW-verified r11c) ----
#if __has_builtin(__builtin_amdgcn_permlane32_swap)
#define HAVE_PLS 1
DEV void plswap01(float &x0, float &x1){
  auto r = __builtin_amdgcn_permlane32_swap(__float_as_uint(x0), __float_as_uint(x1), false, false);
  x0 = __uint_as_float((unsigned)r[0]);
  x1 = __uint_as_float((unsigned)r[1]);
}
#else
#define HAVE_PLS 0
#endif

// gate on register slot bit SB
template<int SB>
DEV void gate4(float2* a, const float* __restrict__ g){
  float u00r=g[0],u00i=g[1],u01r=g[2],u01i=g[3],u10r=g[4],u10i=g[5],u11r=g[6],u11i=g[7];
  #pragma unroll
  for (int m=0;m<2;m++){
    int i0 = (SB==0) ? (m<<1) : m;
    int i1 = i0 | (1<<SB);
    float2 x0=a[i0], x1=a[i1];
    a[i0] = F2(u00r*x0.x - u00i*x0.y + u01r*x1.x - u01i*x1.y,
               u00r*x0.y + u00i*x0.x + u01r*x1.y + u01i*x1.x);
    a[i1] = F2(u10r*x0.x - u10i*x0.y + u11r*x1.x - u11i*x1.y,
               u10r*x0.y + u10i*x0.x + u11r*x1.y + u11i*x1.x);
  }
}

// gate on LANE bit: new = A*self + B*partner, A = h? u11:u00, B = h? u10:u01.
DEV void lgate(float2* a, const float* __restrict__ g, int mask, int lane){
  bool h = (lane & mask) != 0;
  float Ar = h ? g[6] : g[0], Ai = h ? g[7] : g[1];
  float Br = h ? g[4] : g[2], Bi = h ? g[5] : g[3];
  #pragma unroll
  for (int s=0;s<4;s++){
    float px = __shfl_xor(a[s].x, mask);
    float py = __shfl_xor(a[s].y, mask);
    a[s] = F2(Ar*a[s].x - Ai*a[s].y + Br*px - Bi*py,
              Ar*a[s].y + Ai*a[s].x + Br*py + Bi*px);
  }
}

// mask-32 lane gate via permlane32_swap: h=0 -> u00*x0+u01*x1; h=1 -> u10*x0+u11*x1.
DEV void lgate32(float2* a, const float* __restrict__ g, int lane){
#if HAVE_PLS
  bool h = (lane & 32) != 0;
  float c0r = h ? g[4] : g[0], c0i = h ? g[5] : g[1];
  float c1r = h ? g[6] : g[2], c1i = h ? g[7] : g[3];
  #pragma unroll
  for (int s=0;s<4;s++){
    float x0x = a[s].x, x1x = a[s].x, x0y = a[s].y, x1y = a[s].y;
    plswap01(x0x, x1x); plswap01(x0y, x1y);
    a[s] = F2(c0r*x0x - c0i*x0y + c1r*x1x - c1i*x1y,
              c0r*x0y + c0i*x0x + c1r*x1y + c1i*x1x);
  }
#else
  lgate(a, g, 32, lane);
#endif
}

// CNOT ctrl lane-bit cmask, tgt lane-bit tmask
DEV void cswap(float2* a, int cmask, int tmask, int lane){
  bool c = (lane & cmask) != 0;
  #pragma unroll
  for (int s=0;s<4;s++){
    float px = __shfl_xor(a[s].x, tmask);
    float py = __shfl_xor(a[s].y, tmask);
    if (c){ a[s].x = px; a[s].y = py; }
  }
}

// RZZ: couplings [C0,C0+N0) u [C1,C1+N1). hh[k] = theta3(k)/2; Ib = index, reg bits 0.
template<int C0,int N0,int C1,int N1,unsigned M0,unsigned M1>
DEV void diagx(float2* a, const float* __restrict__ hh, unsigned Ib){
  const unsigned rm = M0|M1;
  float base = 0.f;
  #pragma unroll
  for (int k=C0;k<C0+N0;k++){
    const int p=G_CP[k], q=G_CQ[k];
    if (!(((1u<<p)|(1u<<q)) & rm)){
      float h = hh[k];
      base += (((Ib>>p)^(Ib>>q))&1u) ? h : -h;
    }
  }
  #pragma unroll
  for (int k=C1;k<C1+N1;k++){
    const int p=G_CP[k], q=G_CQ[k];
    if (!(((1u<<p)|(1u<<q)) & rm)){
      float h = hh[k];
      base += (((Ib>>p)^(Ib>>q))&1u) ? h : -h;
    }
  }
  #pragma unroll
  for (int r=0;r<4;r++){
    unsigned Ir = Ib ^ ((r&1)?M0:0u) ^ ((r&2)?M1:0u);
    float ph = base;
    #pragma unroll
    for (int k=C0;k<C0+N0;k++){
      const int p=G_CP[k], q=G_CQ[k];
      if (((1u<<p)|(1u<<q)) & rm){
        float h = hh[k];
        ph += (((Ir>>p)^(Ir>>q))&1u) ? h : -h;
      }
    }
    #pragma unroll
    for (int k=C1;k<C1+N1;k++){
      const int p=G_CP[k], q=G_CQ[k];
      if (((1u<<p)|(1u<<q)) & rm){
        float h = hh[k];
        ph += (((Ir>>p)^(Ir>>q))&1u) ? h : -h;
      }
    }
    float c, s;
    __sincosf(ph, &s, &c);
    a[r] = cmulf(a[r], F2(c, s));
  }
}

// ---- per-block gate-table build (f32) ----
DEV void build_entry(float* sh, const float* __restrict__ p0, const float* __restrict__ p1,
                     const float* __restrict__ p2, const float* __restrict__ p3, int g){
  int d, j, n; const float* P;
  if (g < 32)      { n=16; d=(g>>4)&1; j=g&15; P=p0; }
  else if (g < 48) { n=8;  d=(g>>3)&1; j=g&7;  P=p1; }
  else if (g < 56) { n=4;  d=(g>>2)&1; j=g&3;  P=p2; }
  else             { n=2;  d=(g>>1)&1; j=g&1;  P=p3; }
  int base = 4*j + 4*n*d;
  float th0 = P[base+0], th1 = P[base+1], th2 = P[base+2], th3 = P[base+3];
  float c0,s0,ca,sa,c2,s2;
  sincosf(0.5f*th0, &s0, &c0);
  sincosf(0.5f*th1, &sa, &ca);
  sincosf(0.5f*th2, &s2, &c2);
  float B00r =  ca*c0, B00i = -sa*c0;
  float B01r = -sa*s0, B01i = -ca*s0;
  float B10r =  sa*s0, B10i = -ca*s0;
  float B11r =  ca*c0, B11i =  sa*c0;
  float* o8 = sh + g*8;
  o8[0]=c2*B00r + s2*B10i; o8[1]=c2*B00i - s2*B10r;
  o8[2]=c2*B01r + s2*B11i; o8[3]=c2*B01i - s2*B11r;
  o8[4]=s2*B00i + c2*B10r; o8[5]=-s2*B00r + c2*B10i;
  o8[6]=s2*B01i + c2*B11r; o8[7]=-s2*B01r + c2*B11i;
  sh[480 + g] = 0.5f*th3;
}

// ======== pass A: tile j = b0..b11 (identity), outer o = b12..b15 ========
// Layout A: reg=(b0,b1), lane=(b2..b7), wave=(b8..b11)  [j = (t<<2)|s]
// Layout B: reg=(b10,b11), lane=(b8,b9,b6,b7,b4,b5), wave=(b0..b3)
// Store: addr = (batch<<16)|(o<<12)|(wv<<8)|(lane<<2)|s  (linear, wave-contiguous 2KB)
__global__ __launch_bounds__(1024, 4)
void k_pa(const float* __restrict__ xre, const float* __restrict__ xim,
          const float* __restrict__ pp0, const float* __restrict__ pp1,
          const float* __restrict__ pp2, const float* __restrict__ pp3,
          float* __restrict__ tbl, float2* __restrict__ st, float* __restrict__ out){
  const int t = threadIdx.x, lane = t & 63, wv = t >> 6;   // wv 0..15
  const int batch = blockIdx.x >> 4, o = blockIdx.x & 15;
  const unsigned hi = ((unsigned)batch<<16) | ((unsigned)o<<12);
  __shared__ float2 lds[4096];
  __shared__ float sh[544];
  float2 a[4];
  { // load layout A (contiguous; issues before table build)
    unsigned base = hi | ((unsigned)t<<2);
    float4 re = *(const float4*)(xre + base);
    float4 im = *(const float4*)(xim + base);
    a[0]=F2(re.x,im.x); a[1]=F2(re.y,im.y); a[2]=F2(re.z,im.z); a[3]=F2(re.w,im.w);
  }
  if (t < 60) build_entry(sh, pp0, pp1, pp2, pp3, t);
  if (blockIdx.x == 0 && t >= 64 && t < 80) out[t - 64] = 0.f;
  __syncthreads();
  if (blockIdx.x == 0){
    for (int i = t; i < 540; i += 1024) tbl[i] = sh[i];
  }
  #define LTB(i) (sh + (i)*8)
  const float* HH = sh + 480;
  // ---- layout A ----
  gate4<0>(a, LTB(15)); gate4<1>(a, LTB(14));                    // L1d0 b0,b1
  lgate(a, LTB(13),1,lane); lgate(a, LTB(12),2,lane);            // b2,b3
  lgate(a, LTB(11),4,lane); lgate(a, LTB(10),8,lane);            // b4,b5
  lgate(a, LTB(9),16,lane); lgate32(a, LTB(8),lane);             // b6,b7
  const unsigned IbA = ((unsigned)o<<12) | ((unsigned)wv<<8) | ((unsigned)lane<<2);
  diagx<8,7,0,0,1u,2u>(a, HH, IbA);                              // D0 (7,6)..(1,0)
  gate4<1>(a, LTB(30));                                          // L1d1 b1
  lgate(a, LTB(29),1,lane); lgate(a, LTB(28),2,lane);            // b2,b3
  lgate(a, LTB(27),4,lane); lgate(a, LTB(26),8,lane);            // b4,b5
  lgate(a, LTB(25),16,lane);                                     // b6
  diagx<25,5,0,0,1u,2u>(a, HH, IbA);                             // D1 (6,5)..(2,1)
  cswap(a,2,1,lane);                                             // CNOT 3->2
  cswap(a,8,4,lane);                                             // CNOT 5->4
  // ---- exchange ----
  #pragma unroll
  for (int s=0;s<4;s++) lds[swz((t<<2)|s)] = a[s];
  __syncthreads();
  const int idxR = (wv&15) | (((lane>>4)&1)<<4) | (((lane>>5)&1)<<5)
                 | (((lane>>2)&1)<<6) | (((lane>>3)&1)<<7)
                 | ((lane&1)<<8) | (((lane>>1)&1)<<9);
  #pragma unroll
  for (int s=0;s<4;s++) a[s] = lds[swz(idxR | ((s&1)<<10) | (((s>>1)&1)<<11))];
  // ---- layout B ----
  lgate(a, LTB(7),1,lane); lgate(a, LTB(6),2,lane);              // L1d0 b8,b9
  gate4<0>(a, LTB(5)); gate4<1>(a, LTB(4));                      // L1d0 b10,b11
  const unsigned IbB = ((unsigned)o<<12) | (unsigned)idxR;
  diagx<4,4,0,0,1024u,2048u>(a, HH, IbB);                        // D0 (11,10)..(8,7)
  lgate(a, LTB(24),8,lane);                                      // L1d1 b7
  lgate(a, LTB(23),1,lane); lgate(a, LTB(22),2,lane);            // b8,b9
  gate4<0>(a, LTB(21));                                          // b10
  diagx<21,4,0,0,1024u,2048u>(a, HH, IbB);                       // D1 (10,9)..(7,6)
  cswap(a,8,4,lane);                                             // CNOT 7->6
  cswap(a,2,1,lane);                                             // CNOT 9->8
  {
    unsigned sb = hi | ((unsigned)wv<<8) | ((unsigned)lane<<2);
    float4 v0, v1;
    v0.x=a[0].x; v0.y=a[0].y; v0.z=a[1].x; v0.w=a[1].y;
    v1.x=a[2].x; v1.y=a[2].y; v1.z=a[3].x; v1.w=a[3].y;
    *(float4*)(st + sb) = v0;
    *(float4*)(st + sb + 2) = v1;
  }
  #undef LTB
}

#define TBL(i) (tbl + (i)*8)

// ======== pass B: tile m: m0..m11 -> b{0,1,3,5,7,9,10,11,12,13,14,15}; outer b{2,4,6,8}
// Layout A: reg=(b10,b11); lane=(b12,b13,b14,b15,b0,b1); wave=(b3,b5,b7,b9)
// Layout B: reg=(b1,b3); lane=(b5,b7,b9,b11,b13,b15); wave=(b0,b10,b12,b14)  [= r11c p4 tail]
__global__ __launch_bounds__(1024, 4)
void k_pb(const float* __restrict__ tbl, float2* __restrict__ st, float* __restrict__ out){
  const int t = threadIdx.x, lane = t & 63, wv = t >> 6;
  const int batch = blockIdx.x >> 4, o = blockIdx.x & 15;
  __shared__ float2 lds[4096];
  __shared__ float red[16];
  const float* HH = tbl + 480;
  const unsigned opart = ((unsigned)(o&1)<<2) | ((unsigned)((o>>1)&1)<<4)
                       | ((unsigned)((o>>2)&1)<<6) | ((unsigned)((o>>3)&1)<<8);
  float2 a[4];
  { // gather: inverse of pass-A store permutation; 32B contiguous per thread
    unsigned gb = ((unsigned)batch<<16)
      | (((unsigned)(o>>3)&1)<<2) | (((unsigned)(o>>2)&1)<<4)
      | (((unsigned)(o>>1)&1)<<6) | (((unsigned)o&1)<<10)
      | (((unsigned)(wv>>3)&1)<<3) | (((unsigned)(wv>>2)&1)<<5)
      | (((unsigned)(wv>>1)&1)<<7) | (((unsigned)wv&1)<<11)
      | (((unsigned)(lane>>4)&1)<<8) | (((unsigned)(lane>>5)&1)<<9)
      | (((unsigned)lane&1)<<12) | (((unsigned)(lane>>1)&1)<<13)
      | (((unsigned)(lane>>2)&1)<<14) | (((unsigned)(lane>>3)&1)<<15);
    const float4* sp = (const float4*)(st + gb);
    float4 lo = sp[0], hi4 = sp[1];
    a[0]=F2(lo.x,lo.y); a[1]=F2(lo.z,lo.w); a[2]=F2(hi4.x,hi4.y); a[3]=F2(hi4.z,hi4.w);
  }
  const unsigned IbA = opart
    | (((unsigned)lane&1)<<12) | (((unsigned)(lane>>1)&1)<<13)
    | (((unsigned)(lane>>2)&1)<<14) | (((unsigned)(lane>>3)&1)<<15)
    | (((unsigned)(lane>>4)&1)<<0) | (((unsigned)(lane>>5)&1)<<1)
    | (((unsigned)wv&1)<<3) | (((unsigned)(wv>>1)&1)<<5)
    | (((unsigned)(wv>>2)&1)<<7) | (((unsigned)(wv>>3)&1)<<9);
  // ---- layout A ----
  lgate(a, TBL(3),1,lane); lgate(a, TBL(2),2,lane);              // L1d0 b12,b13
  lgate(a, TBL(1),4,lane); lgate(a, TBL(0),8,lane);              // b14,b15
  diagx<0,4,15,1,1024u,2048u>(a, HH, IbA);                       // D0 k0..3,k15
  lgate(a, TBL(31),16,lane);                                     // L1d1 b0
  gate4<1>(a, TBL(20));                                          // L1d1 b11
  lgate(a, TBL(19),1,lane); lgate(a, TBL(18),2,lane);            // b12,b13
  lgate(a, TBL(17),4,lane); lgate(a, TBL(16),8,lane);            // b14,b15
  diagx<16,5,30,2,1024u,2048u>(a, HH, IbA);                      // D1 k16..20,k30,k31
  cswap(a,8,4,lane);                                             // CNOT 15->14
  cswap(a,2,1,lane);                                             // CNOT 13->12
  { float2 tmp=a[2]; a[2]=a[3]; a[3]=tmp; }                      // CNOT 11->10 (reg)
  cswap(a,32,16,lane);                                           // CNOT 1->0
  // ---- exchange ----
  const int idxW = ((lane>>4)&1) | (((lane>>5)&1)<<1)
                 | ((wv&1)<<2) | (((wv>>1)&1)<<3) | (((wv>>2)&1)<<4) | (((wv>>3)&1)<<5)
                 | ((lane&1)<<8) | (((lane>>1)&1)<<9)
                 | (((lane>>2)&1)<<10) | (((lane>>3)&1)<<11);
  #pragma unroll
  for (int s=0;s<4;s++) lds[sw2(idxW | ((s&1)<<6) | (((s>>1)&1)<<7))] = a[s];
  __syncthreads();
  const int idxR = (wv&1) | (((wv>>1)&1)<<6) | (((wv>>2)&1)<<8) | (((wv>>3)&1)<<10)
                 | ((lane&1)<<3) | (((lane>>1)&1)<<4) | (((lane>>2)&1)<<5)
                 | (((lane>>3)&1)<<7) | (((lane>>4)&1)<<9) | (((lane>>5)&1)<<11);
  #pragma unroll
  for (int s=0;s<4;s++) a[s] = lds[sw2(idxR | ((s&1)<<1) | (((s>>1)&1)<<2))];
  // ---- layout B (verbatim r11c p4 tail) ----
  const unsigned IbB = opart
    | (((unsigned)wv&1)<<0) | (((unsigned)(wv>>1)&1)<<10)
    | (((unsigned)(wv>>2)&1)<<12) | (((unsigned)(wv>>3)&1)<<14)
    | (((unsigned)lane&1)<<5) | (((unsigned)(lane>>1)&1)<<7)
    | (((unsigned)(lane>>2)&1)<<9) | (((unsigned)(lane>>3)&1)<<11)
    | (((unsigned)(lane>>4)&1)<<13) | (((unsigned)(lane>>5)&1)<<15);
  // L2d0
  gate4<0>(a, TBL(39)); gate4<1>(a, TBL(38));
  lgate(a, TBL(37),1,lane); lgate(a, TBL(36),2,lane); lgate(a, TBL(35),4,lane);
  lgate(a, TBL(34),8,lane); lgate(a, TBL(33),16,lane); lgate32(a, TBL(32),lane);
  diagx<32,8,0,0,2u,8u>(a, HH, IbB);
  // L2d1
  gate4<0>(a, TBL(47)); gate4<1>(a, TBL(46));
  lgate(a, TBL(45),1,lane); lgate(a, TBL(44),2,lane); lgate(a, TBL(43),4,lane);
  lgate(a, TBL(42),8,lane); lgate(a, TBL(41),16,lane); lgate32(a, TBL(40),lane);
  diagx<40,8,0,0,2u,8u>(a, HH, IbB);
  // sigma2
  cswap(a,32,16,lane); cswap(a,8,4,lane); cswap(a,2,1,lane);
  { float2 tmp=a[2]; a[2]=a[3]; a[3]=tmp; }
  // L3d0
  lgate32(a, TBL(48),lane); lgate(a, TBL(49),8,lane); lgate(a, TBL(50),2,lane);
  gate4<1>(a, TBL(51));
  diagx<48,4,0,0,2u,8u>(a, HH, IbB);
  // L3d1
  lgate32(a, TBL(52),lane); lgate(a, TBL(53),8,lane); lgate(a, TBL(54),2,lane);
  gate4<1>(a, TBL(55));
  diagx<52,4,0,0,2u,8u>(a, HH, IbB);
  // sigma3
  cswap(a,32,8,lane);
  if (lane & 2){
    float2 t0=a[0]; a[0]=a[2]; a[2]=t0;
    float2 t1=a[1]; a[1]=a[3]; a[3]=t1;
  }
  // L4d0 {b15,b7}, D4_0, L4d1 b15 (sigma4, D4_1, L4d1(b7) invariant -> dropped)
  lgate32(a, TBL(56),lane); lgate(a, TBL(57),2,lane);
  diagx<56,2,0,0,2u,8u>(a, HH, IbB);
  lgate32(a, TBL(58),lane);
  // measure Z on b15 = lane bit5
  float sl = 0.f;
  #pragma unroll
  for (int s=0;s<4;s++) sl += a[s].x*a[s].x + a[s].y*a[s].y;
  float sg = (lane & 32) ? -sl : sl;
  #pragma unroll
  for (int off=32; off>0; off>>=1) sg += __shfl_down(sg, off);
  if ((t & 63) == 0) red[wv] = sg;
  __syncthreads();
  if (t == 0){
    float tot = 0.f;
    #pragma unroll
    for (int w=0; w<16; w++) tot += red[w];
    atomicAdd(out + batch, tot);
  }
}

extern "C" void kernel_launch(void* const* d_in, const int* in_sizes, int n_in,
                              void* d_out, int out_size, void* d_ws, size_t ws_size,
                              hipStream_t stream) {
  const float* xre = (const float*)d_in[0];
  const float* xim = (const float*)d_in[1];
  const float* p0  = (const float*)d_in[2];
  const float* p1  = (const float*)d_in[3];
  const float* p2  = (const float*)d_in[4];
  const float* p3  = (const float*)d_in[5];
  float* out = (float*)d_out;
  float2* st = (float2*)d_ws;                           // 8 MB state
  float* tbl = (float*)((char*)d_ws + (8u<<20));        // 540-float gate table

  k_pa<<<256, 1024, 0, stream>>>(xre, xim, p0, p1, p2, p3, tbl, st, out);
  k_pb<<<256, 1024, 0, stream>>>(tbl, st, out);
}